// Round 14
// baseline (723.818 us; speedup 1.0000x reference)
//
#include <hip/hip_runtime.h>
#include <math.h>

#define CDIV(a,b) (((a)+(b)-1)/(b))

typedef _Float16 f16;
typedef _Float16 f16x8 __attribute__((ext_vector_type(8)));
typedef float f32x4 __attribute__((ext_vector_type(4)));

__device__ __forceinline__ float rcpf(float x){ return __builtin_amdgcn_rcpf(x); }
__device__ __forceinline__ float fsig(float x){ return rcpf(1.0f+__expf(-x)); }
__device__ __forceinline__ float ftanh(float x){ float e=__expf(2.0f*x); return 1.0f-2.0f*rcpf(e+1.0f); }

// ---------------- utility ----------------
__global__ void zero_kernel(float* __restrict__ p, size_t n){
  size_t i=(size_t)blockIdx.x*blockDim.x+threadIdx.x;
  size_t st=(size_t)gridDim.x*blockDim.x;
  for(;i<n;i+=st) p[i]=0.0f;
}

// ---------------- fp16 conversion prep ----------------
__global__ void f2h_kernel(const float* __restrict__ s, f16* __restrict__ d, size_t n){
  size_t i=(size_t)blockIdx.x*blockDim.x+threadIdx.x;
  size_t st=(size_t)gridDim.x*blockDim.x;
  for(;i<n;i+=st) d[i]=(f16)s[i];
}
// W [128 in][128 out] -> Wt hi/lo [out][in]
__global__ void wtrans_kernel(const float* __restrict__ W, f16* __restrict__ hi,
                              f16* __restrict__ lo){
  int o=blockIdx.x, i=threadIdx.x;
  float f=W[(size_t)i*128+o];
  f16 h=(f16)f; hi[o*128+i]=h; lo[o*128+i]=(f16)(f-(float)h);
}
// LSTM weights: rows reordered gate-major -> interleaved row' = j*4+gate (fp16 hi only)
__global__ void lstm_wprep(const float* __restrict__ W, f16* __restrict__ hi, int ld){
  int rn=blockIdx.x; int k=threadIdx.x;
  int j=rn>>2, gate=rn&3;
  hi[(size_t)rn*ld+k]=(f16)W[(size_t)(gate*192+j)*ld + k];
}
__global__ void lstm_bprep(const float* __restrict__ bih, const float* __restrict__ bhh,
                           float* __restrict__ bI){
  int rn=blockIdx.x*blockDim.x+threadIdx.x;
  if(rn<768){ int j=rn>>2,g=rn&3; int go=g*192+j; bI[rn]=bih[go]+bhh[go]; }
}

// ---------------- CSR build ----------------
__global__ void hist_kernel(const int* __restrict__ ei, int E, int N, int* __restrict__ deg){
  int e=blockIdx.x*blockDim.x+threadIdx.x;
  if(e>=E+N) return;
  int d=(e<E)? ei[E+e] : (e-E);
  atomicAdd(&deg[d],1);
}
__global__ void scan1_kernel(const int* __restrict__ deg, int* __restrict__ offs,
                             int* __restrict__ bsums, int N){
  __shared__ int sd[1024];
  int t=threadIdx.x;
  int i=blockIdx.x*1024+t;
  int v=(i<N)?deg[i]:0;
  sd[t]=v;
  __syncthreads();
  for(int s=1;s<1024;s<<=1){
    int u=(t>=s)?sd[t-s]:0;
    __syncthreads();
    sd[t]+=u;
    __syncthreads();
  }
  if(i<N) offs[i]=sd[t]-v;
  if(t==1023) bsums[blockIdx.x]=sd[1023];
}
__global__ void scan2_kernel(int* __restrict__ bsums, int* __restrict__ offs, int NB, int N){
  if(threadIdx.x==0&&blockIdx.x==0){
    int run=0;
    for(int b=0;b<NB;b++){int s=bsums[b]; bsums[b]=run; run+=s;}
    offs[N]=run;
  }
}
__global__ void scan3_kernel(int* __restrict__ offs, const int* __restrict__ bsums,
                             int* __restrict__ cursor, int N){
  int i=blockIdx.x*blockDim.x+threadIdx.x;
  if(i<N){
    int o=offs[i]+bsums[i>>10];
    offs[i]=o;
    cursor[i]=o;
  }
}
__global__ void scatter_kernel(const int* __restrict__ ei, int E, int N,
                               int* __restrict__ cursor, int* __restrict__ csr){
  int e=blockIdx.x*blockDim.x+threadIdx.x;
  if(e>=E+N) return;
  int s,d;
  if(e<E){ s=ei[e]; d=ei[E+e]; } else { s=e-E; d=s; }
  int pos=atomicAdd(&cursor[d],1);
  csr[pos]=s;
}

// ---------------- graph offsets: batch is sorted -> binary search ----------------
__global__ void goffs_kernel(const int* __restrict__ batch, int N, int G,
                             int* __restrict__ goffs){
  int g=blockIdx.x*blockDim.x+threadIdx.x;
  if (g>G) return;
  if (g==G){ goffs[G]=N; return; }
  int lo=0, hi=N;
  while (lo<hi){ int mid=(lo+hi)>>1; if (batch[mid]<g) lo=mid+1; else hi=mid; }
  goffs[g]=lo;
}

// ---------------- MFMA GEMM (fp16 in), 128x128 tile, BK=32, fused epilogues ------
// ROUND-10 schedule (proven best): A+B DMA->LDS double-buffer (4x8KB=32KB),
// 1-step prefetch, counted vmcnt(4)/0, two barriers/step. Depth-2 / 3-buffer
// variants (r11,r12) destroyed per-XCD L2 reuse (FETCH 48->640MB) — keep shallow.
// 16B-granule swizzle on stage+read.
// MODE 0: GAT — hi/lo pairs; write htmp f16 + per-head es/ed (nd=1, NXB=1)
// MODE 1: LSTM — fp16-hi, merged fwd+bwd (nd=2): gates, f16 c/h state, scores
struct GemmDesc {
  const f16* aq[2][12];        // [dir][q] A-tile sources (32-K tiles)
  const f16* bq[2][12];        // [dir][q] B-tile sources
  int lda[12], ldb[12];
  int nq, nd, M, GY, NXB;
  // MODE 0
  f16* htmp; const float* as_; const float* ad_; float* es; float* ed;
  // MODE 1
  f16* h16[2]; f16* cbuf[2]; const float* bias[2]; const float* wa[2];
  float* score; int l_out[2]; int firstStep; int lastStep;
};

template<int MODE>
__global__ __launch_bounds__(256) void gemm_mfma(GemmDesc d){
  __shared__ __align__(16) char smraw[33792];   // A 2x8KB + B 2x8KB; EP alias 33.8KB
  const int TILE = 128*32;                      // f16 elems per 8KB tile
  f16* Ab0=(f16*)smraw;      f16* Ab1=Ab0+TILE;
  f16* Bb0=Ab1+TILE;         f16* Bb1=Bb0+TILE;
  float* EP = (float*)smraw;

  // XCD-aware remap: all panels of one row-panel land on one XCD
  const int wg = blockIdx.x;
  const int xcd = wg & 7, kk0 = wg >> 3;
  const int nxt = d.nd * d.NXB;
  const int xbg = kk0 % nxt;
  const int yp  = xcd + 8*(kk0 / nxt);
  if (yp >= d.GY) return;
  const int dir = (xbg >= d.NXB) ? 1 : 0;
  const int xb  = xbg - dir*d.NXB;

  const int t = threadIdx.x;
  const int wv = t>>6, ln = t&63;
  const int m0 = yp*128, n0 = xb*128;
  const int wr = (wv>>1)*64, wc = (wv&1)*64;
  f32x4 acc[4][4];
#pragma unroll
  for(int i=0;i<4;i++)
#pragma unroll
  for(int j=0;j<4;j++) acc[i][j]=(f32x4){0.f,0.f,0.f,0.f};

  // staging: lane covers (row = i*64 + wv*16 + (ln>>2), slot g = ln&3)
  const int gs = ((ln&3) - ((ln>>3)&3)) & 3;           // source granule (lane-const)
  const int gp = ((ln>>4) + (((ln&15)>>1)&3)) & 3;     // read granule (lane-const)

  // precomputed per-lane staging offsets (f16 elems)
  int offA128[2],offA192[2],offB128[2],offB192[2];
#pragma unroll
  for(int i=0;i<2;i++){
    int ga = m0 + i*64 + wv*16 + (ln>>2); if (ga >= d.M) ga = d.M-1;
    int gb = n0 + i*64 + wv*16 + (ln>>2);
    offA128[i]=ga*128+gs*8; offA192[i]=ga*192+gs*8;
    offB128[i]=gb*128+gs*8; offB192[i]=gb*192+gs*8;
  }

  auto issue=[&](int q,int buf){
    const f16* aS=d.aq[dir][q]; const bool wa_=(d.lda[q]==192);
    const f16* bS=d.bq[dir][q]; const bool wb_=(d.ldb[q]==192);
    f16* Adst = buf? Ab1:Ab0;
    f16* Bdst = buf? Bb1:Bb0;
#pragma unroll
    for(int i=0;i<2;i++){
      int offa = wa_? offA192[i]:offA128[i];
      __builtin_amdgcn_global_load_lds(
        (const __attribute__((address_space(1))) unsigned int*)(aS+offa),
        (__attribute__((address_space(3))) unsigned int*)&Adst[(i*64+wv*16)*32],16,0,0);
      int offb = wb_? offB192[i]:offB128[i];
      __builtin_amdgcn_global_load_lds(
        (const __attribute__((address_space(1))) unsigned int*)(bS+offb),
        (__attribute__((address_space(3))) unsigned int*)&Bdst[(i*64+wv*16)*32],16,0,0);
    }
  };

  issue(0,0);
  for (int s=0; s<d.nq; s++){
    const int cur = s&1;
    if (s+1<d.nq){
      issue(s+1,cur^1);
      asm volatile("s_waitcnt vmcnt(4)" ::: "memory");   // step s's 4 loads done
    } else {
      asm volatile("s_waitcnt vmcnt(0)" ::: "memory");
    }
    __builtin_amdgcn_sched_barrier(0);
    __builtin_amdgcn_s_barrier();          // tile s staged by all waves
    __builtin_amdgcn_sched_barrier(0);
    const f16* As = cur? Ab1:Ab0;
    const f16* Bs = cur? Bb1:Bb0;
    f16x8 av[4], bv[4];
#pragma unroll
    for (int i=0;i<4;i++)
      av[i] = *(const f16x8*)&As[(wr + i*16 + (ln&15))*32 + gp*8];
#pragma unroll
    for (int j=0;j<4;j++)
      bv[j] = *(const f16x8*)&Bs[(wc + j*16 + (ln&15))*32 + gp*8];
#pragma unroll
    for (int i=0;i<4;i++)
#pragma unroll
    for (int j=0;j<4;j++)
      acc[i][j] = __builtin_amdgcn_mfma_f32_16x16x32_f16(av[i], bv[j], acc[i][j], 0,0,0);
    __builtin_amdgcn_sched_barrier(0);
    __builtin_amdgcn_s_barrier();          // reads done; next iter may DMA-overwrite
  }

  // ---- fused epilogue: two 64-row phases staged through EP (aliases staging LDS) ----
  const int lc2 = ln&15, lr4 = (ln>>4)*4;
  const int row4 = t>>2, q4 = t&3;     // 64 rows x 4 col-quarters (32 cols each)
#pragma unroll
  for (int ph=0; ph<2; ph++){
    __syncthreads();
    if ((wv>>1) == ph){
#pragma unroll
      for (int i=0;i<4;i++){
#pragma unroll
        for (int jf=0;jf<4;jf++){
          int col = wc + jf*16 + lc2;
#pragma unroll
          for (int r=0;r<4;r++)
            EP[(i*16+lr4+r)*132 + col] = acc[i][jf][r];
        }
      }
    }
    __syncthreads();
    int grow = m0 + ph*64 + row4;
    if (grow < d.M){
      if (MODE==0){
        float s=0.f, dd=0.f;
        const float* asp = d.as_ + q4*32;
        const float* adp = d.ad_ + q4*32;
#pragma unroll
        for (int q8=0;q8<4;q8++){
          f16x8 pk;
#pragma unroll
          for (int r=0;r<8;r++){
            float v = EP[row4*132 + q4*32 + q8*8 + r];
            pk[r] = (f16)v;
            s  += v*asp[q8*8+r];
            dd += v*adp[q8*8+r];
          }
          *(f16x8*)&d.htmp[(size_t)grow*128 + q4*32 + q8*8] = pk;
        }
        d.es[grow*4+q4] = s;
        d.ed[grow*4+q4] = dd;
      } else {
        float sc = 0.f;
        int jg0 = xb*32 + q4*8;
        size_t hbase = (size_t)grow*192 + jg0;
        const float* bI = d.bias[dir] + xb*128 + q4*32;
        f16* h16d = d.h16[dir];
        f16* cbufd = d.cbuf[dir];
        const float* wad = d.wa[dir];
        f16x8 cold8;
        if (!d.firstStep) cold8 = *(const f16x8*)&cbufd[hbase];
        f16x8 hl, cl;
#pragma unroll
        for (int j=0;j<8;j++){
          float4 z = *(float4*)&EP[row4*132 + q4*32 + j*4];
          float zi=z.x+bI[j*4+0], zf=z.y+bI[j*4+1], zg=z.z+bI[j*4+2], zo=z.w+bI[j*4+3];
          float cold = d.firstStep ? 0.f : (float)cold8[j];
          float c = fsig(zf)*cold + fsig(zi)*ftanh(zg);
          float h = fsig(zo)*ftanh(c);
          cl[j] = (f16)c;
          hl[j] = (f16)h;
          sc += h * wad[jg0+j];
        }
        if (!d.lastStep){
          *(f16x8*)&cbufd[hbase] = cl;
          *(f16x8*)&h16d[hbase] = hl;
        }
        sc += __shfl_xor(sc,1);
        sc += __shfl_xor(sc,2);
        if (q4==0) atomicAdd(&d.score[(size_t)grow*3 + d.l_out[dir]], sc);
      }
    }
  }
}

// ---------------- GAT attention: 4 waves per node, interleaved edge chunks -------
// One block per node. Waves take chunks of 2 edges round-robin (serial chain
// ~degree/8 iterations vs ~degree before); partials combined via LDS reduce.
__global__ __launch_bounds__(256) void attn_kernel(const f16* __restrict__ htmp,
   const float* __restrict__ es, const float* __restrict__ ed,
   const int* __restrict__ offs, const int* __restrict__ csr,
   const float* __restrict__ bias, f16* __restrict__ xsl, int N){
  int v=blockIdx.x;
  int wv=threadIdx.x>>6, lane=threadIdx.x&63;
  int hd=lane>>4;          // head for this lane's channels
  int c0=lane*2;
  int beg=offs[v], end=offs[v+1];
  float edv=ed[v*4+hd];
  float ssum=0.f,a0=0.f,a1=0.f;
  for(int i=beg+wv*2; i<end; i+=8){
    int s0=csr[i];
    bool has2=(i+1<end);
    int s1=has2? csr[i+1]:s0;
    float E0=es[s0*4+hd], E1=es[s1*4+hd];
    unsigned u0=*(const unsigned*)&htmp[(size_t)s0*128+c0];
    unsigned u1=*(const unsigned*)&htmp[(size_t)s1*128+c0];
    float e0=E0+edv; e0=(e0>0.f)?e0:0.2f*e0; float x0=__expf(e0);
    float e1=E1+edv; e1=(e1>0.f)?e1:0.2f*e1; float x1=has2?__expf(e1):0.f;
    ssum+=x0+x1;
    union {unsigned u; f16 h[2];} p0,p1;
    p0.u=u0; p1.u=u1;
    a0 += x0*(float)p0.h[0] + x1*(float)p1.h[0];
    a1 += x0*(float)p0.h[1] + x1*(float)p1.h[1];
  }
  __shared__ float red[3][4][64];
  red[0][wv][lane]=a0; red[1][wv][lane]=a1; red[2][wv][lane]=ssum;
  __syncthreads();
  if(wv==0){
    a0  =red[0][0][lane]+red[0][1][lane]+red[0][2][lane]+red[0][3][lane];
    a1  =red[1][0][lane]+red[1][1][lane]+red[1][2][lane]+red[1][3][lane];
    ssum=red[2][0][lane]+red[2][1][lane]+red[2][2][lane]+red[2][3][lane];
    float inv=rcpf(ssum+1e-16f);
    float o0=fmaxf(a0*inv+bias[c0],0.f), o1=fmaxf(a1*inv+bias[c0+1],0.f);
    union { f16 h[2]; unsigned u; } pko;
    pko.h[0]=(f16)o0; pko.h[1]=(f16)o1;
    *reinterpret_cast<unsigned*>(&xsl[(size_t)v*128+c0]) = pko.u;
  }
}

// ---------------- JK softmax + weighted sum + mean-pool: one block per graph ------
__global__ __launch_bounds__(256) void jk_pool_kernel(const f16* __restrict__ xs, size_t xstride,
   const float* __restrict__ score, const int* __restrict__ goffs,
   float* __restrict__ pooled, int G){
  int g=blockIdx.x;
  int beg=goffs[g], end=goffs[g+1];
  int c=threadIdx.x&127, half=threadIdx.x>>7;
  float acc=0.f;
  for(int n=beg+half; n<end; n+=2){
    float s0=score[n*3],s1=score[n*3+1],s2=score[n*3+2];
    float m=fmaxf(s0,fmaxf(s1,s2));
    float e0=__expf(s0-m),e1=__expf(s1-m),e2=__expf(s2-m);
    float inv=rcpf(e0+e1+e2);
    size_t base=(size_t)n*128+c;
    acc += ((float)xs[base]*e0+(float)xs[xstride+base]*e1+(float)xs[2*xstride+base]*e2)*inv;
  }
  __shared__ float red[128];
  if(half==1) red[c]=acc;
  __syncthreads();
  if(half==0){
    float tot=acc+red[c];
    float cnt=(float)(end-beg);
    pooled[(size_t)g*128+c]=tot*rcpf(fmaxf(cnt,1.0f));
  }
}

__global__ __launch_bounds__(128) void final_kernel(const float* __restrict__ pooled,
   const float* __restrict__ Wl, const float* __restrict__ bl,
   float* __restrict__ out, int G){
  int g=blockIdx.x; int c=threadIdx.x;
  float pv=pooled[(size_t)g*128+c];
  float p0=pv*Wl[c*2], p1=pv*Wl[c*2+1];
  for(int s=32;s>=1;s>>=1){ p0+=__shfl_down(p0,s); p1+=__shfl_down(p1,s); }
  __shared__ float sm[4];
  int w=c>>6;
  if((c&63)==0){ sm[w*2]=p0; sm[w*2+1]=p1; }
  __syncthreads();
  if(c==0){
    out[g*2+0]=sm[0]+sm[2]+bl[0];
    out[g*2+1]=sm[1]+sm[3]+bl[1];
  }
}

// ---------------- launch ----------------
extern "C" void kernel_launch(void* const* d_in, const int* in_sizes, int n_in,
                              void* d_out, int out_size, void* d_ws, size_t ws_size,
                              hipStream_t stream) {
  const float* x     = (const float*)d_in[0];
  const int*   ei    = (const int*)d_in[1];
  const int*   batch = (const int*)d_in[2];
  const float* W[3]  = {(const float*)d_in[3],(const float*)d_in[7],(const float*)d_in[11]};
  const float* AS[3] = {(const float*)d_in[4],(const float*)d_in[8],(const float*)d_in[12]};
  const float* AD[3] = {(const float*)d_in[5],(const float*)d_in[9],(const float*)d_in[13]};
  const float* BV[3] = {(const float*)d_in[6],(const float*)d_in[10],(const float*)d_in[14]};
  const float* Wih[2]= {(const float*)d_in[15],(const float*)d_in[19]};
  const float* Whh[2]= {(const float*)d_in[16],(const float*)d_in[20]};
  const float* bih[2]= {(const float*)d_in[17],(const float*)d_in[21]};
  const float* bhh[2]= {(const float*)d_in[18],(const float*)d_in[22]};
  const float* Wa    = (const float*)d_in[23];
  const float* Wl    = (const float*)d_in[25];
  const float* bl    = (const float*)d_in[26];
  float* out = (float*)d_out;

  const int N  = in_sizes[2];
  const int E  = in_sizes[1]/2;
  const int ET = E+N;
  const int G  = out_size/2;
  const int Mpad = CDIV(N,128)*128;
  const int GY = CDIV(N,128);
  const int GYp = CDIV(GY,8)*8;

  // ---- workspace carve (256B aligned) ----
  char* p = (char*)d_ws;
  auto alloc = [&](size_t bytes)->char*{ char* r=p; p += ((bytes+255)/256)*256; return r; };
  // fixed region
  int*   deg    = (int*)  alloc((size_t)N*4);
  int*   offs   = (int*)  alloc((size_t)(N+1)*4);
  int*   cursor = (int*)  alloc((size_t)N*4);
  int*   bsums  = (int*)  alloc((size_t)CDIV(N,1024)*4);
  int*   csr    = (int*)  alloc((size_t)ET*4);
  int*   goffs  = (int*)  alloc((size_t)(G+1)*4);
  f16*   WtH[3], *WtL[3];
  for(int l=0;l<3;l++){ WtH[l]=(f16*)alloc(128*128*2); WtL[l]=(f16*)alloc(128*128*2); }
  f16 *WihH[2],*WhhH[2];
  float* bsumI[2];
  for(int d2=0;d2<2;d2++){
    WihH[d2]=(f16*)alloc(768*128*2);
    WhhH[d2]=(f16*)alloc(768*192*2);
    bsumI[d2]=(float*)alloc(768*4);
  }
  f16*   xs16   = (f16*)  alloc((size_t)3*Mpad*128*2);
  float* score  = (float*)alloc((size_t)N*3*4);
  float* pooled = (float*)alloc((size_t)G*128*4);
  char* P = p;   // phase-overlaid region
  auto al256 = [](size_t b)->size_t{ return ((b+255)/256)*256; };
  // GAT phase overlay
  f16*   x016 = (f16*)P;
  f16*   htmp = (f16*)(P + al256((size_t)Mpad*128*2));
  float* esb  = (float*)((char*)htmp + al256((size_t)Mpad*128*2));
  float* edb  = (float*)((char*)esb + al256((size_t)N*4*4));
  // LSTM phase overlay (GAT buffers dead by then): separate f16 state per direction
  f16*  h16s[2]; f16* cbufs[2];
  {
    char* q = P;
    h16s[0]=(f16*)q;   q += al256((size_t)Mpad*192*2);
    cbufs[0]=(f16*)q;  q += al256((size_t)Mpad*192*2);
    h16s[1]=(f16*)q;   q += al256((size_t)Mpad*192*2);
    cbufs[1]=(f16*)q;
  }

  const size_t xstride = (size_t)Mpad*128;

  // ---- 0. weight/input prep ----
  f2h_kernel<<<512,256,0,stream>>>(x, x016, (size_t)N*128);
  for(int l=0;l<3;l++) wtrans_kernel<<<128,128,0,stream>>>(W[l], WtH[l], WtL[l]);
  for(int d2=0;d2<2;d2++){
    lstm_wprep<<<768,128,0,stream>>>(Wih[d2], WihH[d2], 128);
    lstm_wprep<<<768,192,0,stream>>>(Whh[d2], WhhH[d2], 192);
    lstm_bprep<<<3,256,0,stream>>>(bih[d2], bhh[d2], bsumI[d2]);
  }
  zero_kernel<<<64,256,0,stream>>>(score,(size_t)N*3);
  goffs_kernel<<<CDIV(G+1,256),256,0,stream>>>(batch,N,G,goffs);

  // ---- 1. CSR build ----
  zero_kernel<<<64,256,0,stream>>>((float*)deg,(size_t)N);
  hist_kernel<<<CDIV(ET,256),256,0,stream>>>(ei,E,N,deg);
  int NB = CDIV(N,1024);
  scan1_kernel<<<NB,1024,0,stream>>>(deg,offs,bsums,N);
  scan2_kernel<<<1,64,0,stream>>>(bsums,offs,NB,N);
  scan3_kernel<<<CDIV(N,256),256,0,stream>>>(offs,bsums,cursor,N);
  scatter_kernel<<<CDIV(ET,256),256,0,stream>>>(ei,E,N,cursor,csr);

  // ---- 2. GAT layers (A fp16, B hi/lo pair list; fused htmp/es/ed epilogue) ----
  const f16* ain = x016;
  for (int l=0; l<3; l++){
    GemmDesc gd{};
    gd.nq=8; gd.nd=1; gd.M=N; gd.GY=GY; gd.NXB=1;
    gd.htmp=htmp; gd.as_=AS[l]; gd.ad_=AD[l]; gd.es=esb; gd.ed=edb;
    for(int qq=0;qq<4;qq++){
      gd.aq[0][2*qq+0]=ain+qq*32;  gd.bq[0][2*qq+0]=WtH[l]+qq*32;
      gd.aq[0][2*qq+1]=ain+qq*32;  gd.bq[0][2*qq+1]=WtL[l]+qq*32;
    }
    for(int qq=0;qq<8;qq++){ gd.lda[qq]=128; gd.ldb[qq]=128; }
    gemm_mfma<0><<<GYp,256,0,stream>>>(gd);
    attn_kernel<<<N,256,0,stream>>>(htmp,esb,edb,offs,csr,BV[l],
                                    xs16+(size_t)l*xstride,N);
    ain = xs16+(size_t)l*xstride;
  }

  // ---- 3. bidirectional LSTM (fp16-hi weights): fwd+bwd merged, gates+scores fused ----
  for (int st=0; st<3; st++){
    GemmDesc gd{};
    gd.nd=2; gd.NXB=6; gd.M=N; gd.GY=GY;
    gd.nq = (st==0)?4:10;
    gd.score=score; gd.firstStep=(st==0); gd.lastStep=(st==2);
    for(int dir2=0;dir2<2;dir2++){
      int l_in = dir2? (2-st):st;
      gd.l_out[dir2]=l_in;
      const f16* xt = xs16 + (size_t)l_in*xstride;
      gd.h16[dir2]=h16s[dir2]; gd.cbuf[dir2]=cbufs[dir2];
      gd.bias[dir2]=bsumI[dir2]; gd.wa[dir2]=Wa+dir2*192;
      for(int qq=0;qq<4;qq++){
        gd.aq[dir2][qq]=xt+qq*32;
        gd.bq[dir2][qq]=WihH[dir2]+qq*32;
      }
      for(int qq=4;qq<10;qq++){
        gd.aq[dir2][qq]=h16s[dir2]+(qq-4)*32;
        gd.bq[dir2][qq]=WhhH[dir2]+(qq-4)*32;
      }
    }
    for(int qq=0;qq<4;qq++){ gd.lda[qq]=128; gd.ldb[qq]=128; }
    for(int qq=4;qq<10;qq++){ gd.lda[qq]=192; gd.ldb[qq]=192; }
    gemm_mfma<1><<<12*GYp,256,0,stream>>>(gd);
  }

  // ---- 4. JK attention + pooling + final linear ----
  jk_pool_kernel<<<G,256,0,stream>>>(xs16,xstride,score,goffs,pooled,G);
  final_kernel<<<G,128,0,stream>>>(pooled,Wl,bl,out,G);
}

// Round 15
// 599.683 us; speedup vs baseline: 1.2070x; 1.2070x over previous
//
#include <hip/hip_runtime.h>
#include <math.h>

#define CDIV(a,b) (((a)+(b)-1)/(b))

typedef _Float16 f16;
typedef _Float16 f16x8 __attribute__((ext_vector_type(8)));
typedef float f32x4 __attribute__((ext_vector_type(4)));

__device__ __forceinline__ float rcpf(float x){ return __builtin_amdgcn_rcpf(x); }
__device__ __forceinline__ float fsig(float x){ return rcpf(1.0f+__expf(-x)); }
__device__ __forceinline__ float ftanh(float x){ float e=__expf(2.0f*x); return 1.0f-2.0f*rcpf(e+1.0f); }

// ---------------- utility ----------------
__global__ void zero_kernel(float* __restrict__ p, size_t n){
  size_t i=(size_t)blockIdx.x*blockDim.x+threadIdx.x;
  size_t st=(size_t)gridDim.x*blockDim.x;
  for(;i<n;i+=st) p[i]=0.0f;
}

// ---------------- fp16 conversion prep ----------------
__global__ void f2h_kernel(const float* __restrict__ s, f16* __restrict__ d, size_t n){
  size_t i=(size_t)blockIdx.x*blockDim.x+threadIdx.x;
  size_t st=(size_t)gridDim.x*blockDim.x;
  for(;i<n;i+=st) d[i]=(f16)s[i];
}
// W [128 in][128 out] -> Wt hi/lo [out][in]
__global__ void wtrans_kernel(const float* __restrict__ W, f16* __restrict__ hi,
                              f16* __restrict__ lo){
  int o=blockIdx.x, i=threadIdx.x;
  float f=W[(size_t)i*128+o];
  f16 h=(f16)f; hi[o*128+i]=h; lo[o*128+i]=(f16)(f-(float)h);
}
// LSTM weights: rows reordered gate-major -> interleaved row' = j*4+gate (fp16 hi only)
__global__ void lstm_wprep(const float* __restrict__ W, f16* __restrict__ hi, int ld){
  int rn=blockIdx.x; int k=threadIdx.x;
  int j=rn>>2, gate=rn&3;
  hi[(size_t)rn*ld+k]=(f16)W[(size_t)(gate*192+j)*ld + k];
}
__global__ void lstm_bprep(const float* __restrict__ bih, const float* __restrict__ bhh,
                           float* __restrict__ bI){
  int rn=blockIdx.x*blockDim.x+threadIdx.x;
  if(rn<768){ int j=rn>>2,g=rn&3; int go=g*192+j; bI[rn]=bih[go]+bhh[go]; }
}

// ---------------- CSR build ----------------
__global__ void hist_kernel(const int* __restrict__ ei, int E, int N, int* __restrict__ deg){
  int e=blockIdx.x*blockDim.x+threadIdx.x;
  if(e>=E+N) return;
  int d=(e<E)? ei[E+e] : (e-E);
  atomicAdd(&deg[d],1);
}
__global__ void scan1_kernel(const int* __restrict__ deg, int* __restrict__ offs,
                             int* __restrict__ bsums, int N){
  __shared__ int sd[1024];
  int t=threadIdx.x;
  int i=blockIdx.x*1024+t;
  int v=(i<N)?deg[i]:0;
  sd[t]=v;
  __syncthreads();
  for(int s=1;s<1024;s<<=1){
    int u=(t>=s)?sd[t-s]:0;
    __syncthreads();
    sd[t]+=u;
    __syncthreads();
  }
  if(i<N) offs[i]=sd[t]-v;
  if(t==1023) bsums[blockIdx.x]=sd[1023];
}
__global__ void scan2_kernel(int* __restrict__ bsums, int* __restrict__ offs, int NB, int N){
  if(threadIdx.x==0&&blockIdx.x==0){
    int run=0;
    for(int b=0;b<NB;b++){int s=bsums[b]; bsums[b]=run; run+=s;}
    offs[N]=run;
  }
}
__global__ void scan3_kernel(int* __restrict__ offs, const int* __restrict__ bsums,
                             int* __restrict__ cursor, int N){
  int i=blockIdx.x*blockDim.x+threadIdx.x;
  if(i<N){
    int o=offs[i]+bsums[i>>10];
    offs[i]=o;
    cursor[i]=o;
  }
}
__global__ void scatter_kernel(const int* __restrict__ ei, int E, int N,
                               int* __restrict__ cursor, int* __restrict__ csr){
  int e=blockIdx.x*blockDim.x+threadIdx.x;
  if(e>=E+N) return;
  int s,d;
  if(e<E){ s=ei[e]; d=ei[E+e]; } else { s=e-E; d=s; }
  int pos=atomicAdd(&cursor[d],1);
  csr[pos]=s;
}

// ---------------- graph offsets: batch is sorted -> binary search ----------------
__global__ void goffs_kernel(const int* __restrict__ batch, int N, int G,
                             int* __restrict__ goffs){
  int g=blockIdx.x*blockDim.x+threadIdx.x;
  if (g>G) return;
  if (g==G){ goffs[G]=N; return; }
  int lo=0, hi=N;
  while (lo<hi){ int mid=(lo+hi)>>1; if (batch[mid]<g) lo=mid+1; else hi=mid; }
  goffs[g]=lo;
}

// ---------------- MFMA GEMM (fp16 in), 128x128 tile, BK=32, fused epilogues ------
// ROUND-10 schedule (proven best): A+B DMA->LDS double-buffer (4x8KB=32KB),
// 1-step prefetch, counted vmcnt(4)/0, two barriers/step. Depth-2 / 3-buffer
// variants (r11,r12) destroyed per-XCD L2 reuse (FETCH 48->640MB) — keep shallow.
// 16B-granule swizzle on stage+read.
// MODE 0: GAT — hi/lo pairs; write htmp f16 + per-head es/ed (nd=1, NXB=1)
// MODE 1: LSTM — fp16-hi, merged fwd+bwd (nd=2): gates, f16 c/h state, scores
struct GemmDesc {
  const f16* aq[2][12];        // [dir][q] A-tile sources (32-K tiles)
  const f16* bq[2][12];        // [dir][q] B-tile sources
  int lda[12], ldb[12];
  int nq, nd, M, GY, NXB;
  // MODE 0
  f16* htmp; const float* as_; const float* ad_; float* es; float* ed;
  // MODE 1
  f16* h16[2]; f16* cbuf[2]; const float* bias[2]; const float* wa[2];
  float* score; int l_out[2]; int firstStep; int lastStep;
};

template<int MODE>
__global__ __launch_bounds__(256) void gemm_mfma(GemmDesc d){
  __shared__ __align__(16) char smraw[33792];   // A 2x8KB + B 2x8KB; EP alias 33.8KB
  const int TILE = 128*32;                      // f16 elems per 8KB tile
  f16* Ab0=(f16*)smraw;      f16* Ab1=Ab0+TILE;
  f16* Bb0=Ab1+TILE;         f16* Bb1=Bb0+TILE;
  float* EP = (float*)smraw;

  // XCD-aware remap: all panels of one row-panel land on one XCD
  const int wg = blockIdx.x;
  const int xcd = wg & 7, kk0 = wg >> 3;
  const int nxt = d.nd * d.NXB;
  const int xbg = kk0 % nxt;
  const int yp  = xcd + 8*(kk0 / nxt);
  if (yp >= d.GY) return;
  const int dir = (xbg >= d.NXB) ? 1 : 0;
  const int xb  = xbg - dir*d.NXB;

  const int t = threadIdx.x;
  const int wv = t>>6, ln = t&63;
  const int m0 = yp*128, n0 = xb*128;
  const int wr = (wv>>1)*64, wc = (wv&1)*64;
  f32x4 acc[4][4];
#pragma unroll
  for(int i=0;i<4;i++)
#pragma unroll
  for(int j=0;j<4;j++) acc[i][j]=(f32x4){0.f,0.f,0.f,0.f};

  // staging: lane covers (row = i*64 + wv*16 + (ln>>2), slot g = ln&3)
  const int gs = ((ln&3) - ((ln>>3)&3)) & 3;           // source granule (lane-const)
  const int gp = ((ln>>4) + (((ln&15)>>1)&3)) & 3;     // read granule (lane-const)

  // precomputed per-lane staging offsets (f16 elems)
  int offA128[2],offA192[2],offB128[2],offB192[2];
#pragma unroll
  for(int i=0;i<2;i++){
    int ga = m0 + i*64 + wv*16 + (ln>>2); if (ga >= d.M) ga = d.M-1;
    int gb = n0 + i*64 + wv*16 + (ln>>2);
    offA128[i]=ga*128+gs*8; offA192[i]=ga*192+gs*8;
    offB128[i]=gb*128+gs*8; offB192[i]=gb*192+gs*8;
  }

  auto issue=[&](int q,int buf){
    const f16* aS=d.aq[dir][q]; const bool wa_=(d.lda[q]==192);
    const f16* bS=d.bq[dir][q]; const bool wb_=(d.ldb[q]==192);
    f16* Adst = buf? Ab1:Ab0;
    f16* Bdst = buf? Bb1:Bb0;
#pragma unroll
    for(int i=0;i<2;i++){
      int offa = wa_? offA192[i]:offA128[i];
      __builtin_amdgcn_global_load_lds(
        (const __attribute__((address_space(1))) unsigned int*)(aS+offa),
        (__attribute__((address_space(3))) unsigned int*)&Adst[(i*64+wv*16)*32],16,0,0);
      int offb = wb_? offB192[i]:offB128[i];
      __builtin_amdgcn_global_load_lds(
        (const __attribute__((address_space(1))) unsigned int*)(bS+offb),
        (__attribute__((address_space(3))) unsigned int*)&Bdst[(i*64+wv*16)*32],16,0,0);
    }
  };

  issue(0,0);
  for (int s=0; s<d.nq; s++){
    const int cur = s&1;
    if (s+1<d.nq){
      issue(s+1,cur^1);
      asm volatile("s_waitcnt vmcnt(4)" ::: "memory");   // step s's 4 loads done
    } else {
      asm volatile("s_waitcnt vmcnt(0)" ::: "memory");
    }
    __builtin_amdgcn_sched_barrier(0);
    __builtin_amdgcn_s_barrier();          // tile s staged by all waves
    __builtin_amdgcn_sched_barrier(0);
    const f16* As = cur? Ab1:Ab0;
    const f16* Bs = cur? Bb1:Bb0;
    f16x8 av[4], bv[4];
#pragma unroll
    for (int i=0;i<4;i++)
      av[i] = *(const f16x8*)&As[(wr + i*16 + (ln&15))*32 + gp*8];
#pragma unroll
    for (int j=0;j<4;j++)
      bv[j] = *(const f16x8*)&Bs[(wc + j*16 + (ln&15))*32 + gp*8];
#pragma unroll
    for (int i=0;i<4;i++)
#pragma unroll
    for (int j=0;j<4;j++)
      acc[i][j] = __builtin_amdgcn_mfma_f32_16x16x32_f16(av[i], bv[j], acc[i][j], 0,0,0);
    __builtin_amdgcn_sched_barrier(0);
    __builtin_amdgcn_s_barrier();          // reads done; next iter may DMA-overwrite
  }

  // ---- fused epilogue: two 64-row phases staged through EP (aliases staging LDS) ----
  const int lc2 = ln&15, lr4 = (ln>>4)*4;
  const int row4 = t>>2, q4 = t&3;     // 64 rows x 4 col-quarters (32 cols each)
#pragma unroll
  for (int ph=0; ph<2; ph++){
    __syncthreads();
    if ((wv>>1) == ph){
#pragma unroll
      for (int i=0;i<4;i++){
#pragma unroll
        for (int jf=0;jf<4;jf++){
          int col = wc + jf*16 + lc2;
#pragma unroll
          for (int r=0;r<4;r++)
            EP[(i*16+lr4+r)*132 + col] = acc[i][jf][r];
        }
      }
    }
    __syncthreads();
    int grow = m0 + ph*64 + row4;
    if (grow < d.M){
      if (MODE==0){
        float s=0.f, dd=0.f;
        const float* asp = d.as_ + q4*32;
        const float* adp = d.ad_ + q4*32;
#pragma unroll
        for (int q8=0;q8<4;q8++){
          f16x8 pk;
#pragma unroll
          for (int r=0;r<8;r++){
            float v = EP[row4*132 + q4*32 + q8*8 + r];
            pk[r] = (f16)v;
            s  += v*asp[q8*8+r];
            dd += v*adp[q8*8+r];
          }
          *(f16x8*)&d.htmp[(size_t)grow*128 + q4*32 + q8*8] = pk;
        }
        d.es[grow*4+q4] = s;
        d.ed[grow*4+q4] = dd;
      } else {
        float sc = 0.f;
        int jg0 = xb*32 + q4*8;
        size_t hbase = (size_t)grow*192 + jg0;
        const float* bI = d.bias[dir] + xb*128 + q4*32;
        f16* h16d = d.h16[dir];
        f16* cbufd = d.cbuf[dir];
        const float* wad = d.wa[dir];
        f16x8 cold8;
        if (!d.firstStep) cold8 = *(const f16x8*)&cbufd[hbase];
        f16x8 hl, cl;
#pragma unroll
        for (int j=0;j<8;j++){
          float4 z = *(float4*)&EP[row4*132 + q4*32 + j*4];
          float zi=z.x+bI[j*4+0], zf=z.y+bI[j*4+1], zg=z.z+bI[j*4+2], zo=z.w+bI[j*4+3];
          float cold = d.firstStep ? 0.f : (float)cold8[j];
          float c = fsig(zf)*cold + fsig(zi)*ftanh(zg);
          float h = fsig(zo)*ftanh(c);
          cl[j] = (f16)c;
          hl[j] = (f16)h;
          sc += h * wad[jg0+j];
        }
        if (!d.lastStep){
          *(f16x8*)&cbufd[hbase] = cl;
          *(f16x8*)&h16d[hbase] = hl;
        }
        sc += __shfl_xor(sc,1);
        sc += __shfl_xor(sc,2);
        if (q4==0) atomicAdd(&d.score[(size_t)grow*3 + d.l_out[dir]], sc);
      }
    }
  }
}

// ---------------- GAT attention: single pass, f16 gather, 8x batched loads --------
__global__ __launch_bounds__(256) void attn_kernel(const f16* __restrict__ htmp,
   const float* __restrict__ es, const float* __restrict__ ed,
   const int* __restrict__ offs, const int* __restrict__ csr,
   const float* __restrict__ bias, f16* __restrict__ xsl, int N){
  int v=blockIdx.x*4+(threadIdx.x>>6);
  if(v>=N) return;
  int lane=threadIdx.x&63;
  int hd=lane>>4;          // head for this lane's channels
  int c0=lane*2;
  int beg=offs[v], end=offs[v+1];
  float edv=ed[v*4+hd];
  float ssum=0.f,a0=0.f,a1=0.f;
  int i=beg;
  for(; i+8<=end; i+=8){
    int sv[8];
#pragma unroll
    for(int k=0;k<8;k++) sv[k]=csr[i+k];
    float Ev[8]; unsigned uv[8];
#pragma unroll
    for(int k=0;k<8;k++){
      Ev[k]=es[sv[k]*4+hd];
      uv[k]=*(const unsigned*)&htmp[(size_t)sv[k]*128+c0];
    }
#pragma unroll
    for(int k=0;k<8;k++){
      float e=Ev[k]+edv; e=(e>0.f)?e:0.2f*e;
      float x=__expf(e);
      ssum+=x;
      union {unsigned u; f16 h[2];} pk; pk.u=uv[k];
      a0+=x*(float)pk.h[0]; a1+=x*(float)pk.h[1];
    }
  }
  for(; i+4<=end; i+=4){
    int s0=csr[i],s1=csr[i+1],s2=csr[i+2],s3=csr[i+3];
    float E0=es[s0*4+hd],E1=es[s1*4+hd],E2=es[s2*4+hd],E3=es[s3*4+hd];
    unsigned u0=*(const unsigned*)&htmp[(size_t)s0*128+c0];
    unsigned u1=*(const unsigned*)&htmp[(size_t)s1*128+c0];
    unsigned u2=*(const unsigned*)&htmp[(size_t)s2*128+c0];
    unsigned u3=*(const unsigned*)&htmp[(size_t)s3*128+c0];
    float e0=E0+edv; e0=(e0>0.f)?e0:0.2f*e0; float x0=__expf(e0);
    float e1=E1+edv; e1=(e1>0.f)?e1:0.2f*e1; float x1=__expf(e1);
    float e2=E2+edv; e2=(e2>0.f)?e2:0.2f*e2; float x2=__expf(e2);
    float e3=E3+edv; e3=(e3>0.f)?e3:0.2f*e3; float x3=__expf(e3);
    ssum += (x0+x1)+(x2+x3);
    union {unsigned u; f16 h[2];} p0,p1,p2,p3;
    p0.u=u0; p1.u=u1; p2.u=u2; p3.u=u3;
    a0 += x0*(float)p0.h[0] + x1*(float)p1.h[0] + x2*(float)p2.h[0] + x3*(float)p3.h[0];
    a1 += x0*(float)p0.h[1] + x1*(float)p1.h[1] + x2*(float)p2.h[1] + x3*(float)p3.h[1];
  }
  for(; i<end; i++){
    int s=csr[i];
    float e=es[s*4+hd]+edv;
    e=(e>0.f)?e:0.2f*e;
    float ex=__expf(e);
    ssum+=ex;
    union {unsigned u; f16 h[2];} pk;
    pk.u = *reinterpret_cast<const unsigned*>(&htmp[(size_t)s*128+c0]);
    a0+=ex*(float)pk.h[0]; a1+=ex*(float)pk.h[1];
  }
  float inv=1.0f/(ssum+1e-16f);
  float o0=fmaxf(a0*inv+bias[c0],0.f), o1=fmaxf(a1*inv+bias[c0+1],0.f);
  union { f16 h[2]; unsigned u; } pko;
  pko.h[0]=(f16)o0; pko.h[1]=(f16)o1;
  *reinterpret_cast<unsigned*>(&xsl[(size_t)v*128+c0]) = pko.u;
}

// ---------------- JK softmax + weighted sum + mean-pool: one block per graph ------
__global__ __launch_bounds__(256) void jk_pool_kernel(const f16* __restrict__ xs, size_t xstride,
   const float* __restrict__ score, const int* __restrict__ goffs,
   float* __restrict__ pooled, int G){
  int g=blockIdx.x;
  int beg=goffs[g], end=goffs[g+1];
  int c=threadIdx.x&127, half=threadIdx.x>>7;
  float acc=0.f;
  for(int n=beg+half; n<end; n+=2){
    float s0=score[n*3],s1=score[n*3+1],s2=score[n*3+2];
    float m=fmaxf(s0,fmaxf(s1,s2));
    float e0=__expf(s0-m),e1=__expf(s1-m),e2=__expf(s2-m);
    float inv=rcpf(e0+e1+e2);
    size_t base=(size_t)n*128+c;
    acc += ((float)xs[base]*e0+(float)xs[xstride+base]*e1+(float)xs[2*xstride+base]*e2)*inv;
  }
  __shared__ float red[128];
  if(half==1) red[c]=acc;
  __syncthreads();
  if(half==0){
    float tot=acc+red[c];
    float cnt=(float)(end-beg);
    pooled[(size_t)g*128+c]=tot*rcpf(fmaxf(cnt,1.0f));
  }
}

__global__ __launch_bounds__(128) void final_kernel(const float* __restrict__ pooled,
   const float* __restrict__ Wl, const float* __restrict__ bl,
   float* __restrict__ out, int G){
  int g=blockIdx.x; int c=threadIdx.x;
  float pv=pooled[(size_t)g*128+c];
  float p0=pv*Wl[c*2], p1=pv*Wl[c*2+1];
  for(int s=32;s>=1;s>>=1){ p0+=__shfl_down(p0,s); p1+=__shfl_down(p1,s); }
  __shared__ float sm[4];
  int w=c>>6;
  if((c&63)==0){ sm[w*2]=p0; sm[w*2+1]=p1; }
  __syncthreads();
  if(c==0){
    out[g*2+0]=sm[0]+sm[2]+bl[0];
    out[g*2+1]=sm[1]+sm[3]+bl[1];
  }
}

// ---------------- launch ----------------
extern "C" void kernel_launch(void* const* d_in, const int* in_sizes, int n_in,
                              void* d_out, int out_size, void* d_ws, size_t ws_size,
                              hipStream_t stream) {
  const float* x     = (const float*)d_in[0];
  const int*   ei    = (const int*)d_in[1];
  const int*   batch = (const int*)d_in[2];
  const float* W[3]  = {(const float*)d_in[3],(const float*)d_in[7],(const float*)d_in[11]};
  const float* AS[3] = {(const float*)d_in[4],(const float*)d_in[8],(const float*)d_in[12]};
  const float* AD[3] = {(const float*)d_in[5],(const float*)d_in[9],(const float*)d_in[13]};
  const float* BV[3] = {(const float*)d_in[6],(const float*)d_in[10],(const float*)d_in[14]};
  const float* Wih[2]= {(const float*)d_in[15],(const float*)d_in[19]};
  const float* Whh[2]= {(const float*)d_in[16],(const float*)d_in[20]};
  const float* bih[2]= {(const float*)d_in[17],(const float*)d_in[21]};
  const float* bhh[2]= {(const float*)d_in[18],(const float*)d_in[22]};
  const float* Wa    = (const float*)d_in[23];
  const float* Wl    = (const float*)d_in[25];
  const float* bl    = (const float*)d_in[26];
  float* out = (float*)d_out;

  const int N  = in_sizes[2];
  const int E  = in_sizes[1]/2;
  const int ET = E+N;
  const int G  = out_size/2;
  const int Mpad = CDIV(N,128)*128;
  const int GY = CDIV(N,128);
  const int GYp = CDIV(GY,8)*8;

  // ---- workspace carve (256B aligned) ----
  char* p = (char*)d_ws;
  auto alloc = [&](size_t bytes)->char*{ char* r=p; p += ((bytes+255)/256)*256; return r; };
  // fixed region
  int*   deg    = (int*)  alloc((size_t)N*4);
  int*   offs   = (int*)  alloc((size_t)(N+1)*4);
  int*   cursor = (int*)  alloc((size_t)N*4);
  int*   bsums  = (int*)  alloc((size_t)CDIV(N,1024)*4);
  int*   csr    = (int*)  alloc((size_t)ET*4);
  int*   goffs  = (int*)  alloc((size_t)(G+1)*4);
  f16*   WtH[3], *WtL[3];
  for(int l=0;l<3;l++){ WtH[l]=(f16*)alloc(128*128*2); WtL[l]=(f16*)alloc(128*128*2); }
  f16 *WihH[2],*WhhH[2];
  float* bsumI[2];
  for(int d2=0;d2<2;d2++){
    WihH[d2]=(f16*)alloc(768*128*2);
    WhhH[d2]=(f16*)alloc(768*192*2);
    bsumI[d2]=(float*)alloc(768*4);
  }
  f16*   xs16   = (f16*)  alloc((size_t)3*Mpad*128*2);
  float* score  = (float*)alloc((size_t)N*3*4);
  float* pooled = (float*)alloc((size_t)G*128*4);
  char* P = p;   // phase-overlaid region
  auto al256 = [](size_t b)->size_t{ return ((b+255)/256)*256; };
  // GAT phase overlay
  f16*   x016 = (f16*)P;
  f16*   htmp = (f16*)(P + al256((size_t)Mpad*128*2));
  float* esb  = (float*)((char*)htmp + al256((size_t)Mpad*128*2));
  float* edb  = (float*)((char*)esb + al256((size_t)N*4*4));
  // LSTM phase overlay (GAT buffers dead by then): separate f16 state per direction
  f16*  h16s[2]; f16* cbufs[2];
  {
    char* q = P;
    h16s[0]=(f16*)q;   q += al256((size_t)Mpad*192*2);
    cbufs[0]=(f16*)q;  q += al256((size_t)Mpad*192*2);
    h16s[1]=(f16*)q;   q += al256((size_t)Mpad*192*2);
    cbufs[1]=(f16*)q;
  }

  const size_t xstride = (size_t)Mpad*128;

  // ---- 0. weight/input prep ----
  f2h_kernel<<<512,256,0,stream>>>(x, x016, (size_t)N*128);
  for(int l=0;l<3;l++) wtrans_kernel<<<128,128,0,stream>>>(W[l], WtH[l], WtL[l]);
  for(int d2=0;d2<2;d2++){
    lstm_wprep<<<768,128,0,stream>>>(Wih[d2], WihH[d2], 128);
    lstm_wprep<<<768,192,0,stream>>>(Whh[d2], WhhH[d2], 192);
    lstm_bprep<<<3,256,0,stream>>>(bih[d2], bhh[d2], bsumI[d2]);
  }
  zero_kernel<<<64,256,0,stream>>>(score,(size_t)N*3);
  goffs_kernel<<<CDIV(G+1,256),256,0,stream>>>(batch,N,G,goffs);

  // ---- 1. CSR build ----
  zero_kernel<<<64,256,0,stream>>>((float*)deg,(size_t)N);
  hist_kernel<<<CDIV(ET,256),256,0,stream>>>(ei,E,N,deg);
  int NB = CDIV(N,1024);
  scan1_kernel<<<NB,1024,0,stream>>>(deg,offs,bsums,N);
  scan2_kernel<<<1,64,0,stream>>>(bsums,offs,NB,N);
  scan3_kernel<<<CDIV(N,256),256,0,stream>>>(offs,bsums,cursor,N);
  scatter_kernel<<<CDIV(ET,256),256,0,stream>>>(ei,E,N,cursor,csr);

  // ---- 2. GAT layers (A fp16, B hi/lo pair list; fused htmp/es/ed epilogue) ----
  const f16* ain = x016;
  for (int l=0; l<3; l++){
    GemmDesc gd{};
    gd.nq=8; gd.nd=1; gd.M=N; gd.GY=GY; gd.NXB=1;
    gd.htmp=htmp; gd.as_=AS[l]; gd.ad_=AD[l]; gd.es=esb; gd.ed=edb;
    for(int qq=0;qq<4;qq++){
      gd.aq[0][2*qq+0]=ain+qq*32;  gd.bq[0][2*qq+0]=WtH[l]+qq*32;
      gd.aq[0][2*qq+1]=ain+qq*32;  gd.bq[0][2*qq+1]=WtL[l]+qq*32;
    }
    for(int qq=0;qq<8;qq++){ gd.lda[qq]=128; gd.ldb[qq]=128; }
    gemm_mfma<0><<<GYp,256,0,stream>>>(gd);
    attn_kernel<<<CDIV(N,4),256,0,stream>>>(htmp,esb,edb,offs,csr,BV[l],
                                            xs16+(size_t)l*xstride,N);
    ain = xs16+(size_t)l*xstride;
  }

  // ---- 3. bidirectional LSTM (fp16-hi weights): fwd+bwd merged, gates+scores fused ----
  for (int st=0; st<3; st++){
    GemmDesc gd{};
    gd.nd=2; gd.NXB=6; gd.M=N; gd.GY=GY;
    gd.nq = (st==0)?4:10;
    gd.score=score; gd.firstStep=(st==0); gd.lastStep=(st==2);
    for(int dir2=0;dir2<2;dir2++){
      int l_in = dir2? (2-st):st;
      gd.l_out[dir2]=l_in;
      const f16* xt = xs16 + (size_t)l_in*xstride;
      gd.h16[dir2]=h16s[dir2]; gd.cbuf[dir2]=cbufs[dir2];
      gd.bias[dir2]=bsumI[dir2]; gd.wa[dir2]=Wa+dir2*192;
      for(int qq=0;qq<4;qq++){
        gd.aq[dir2][qq]=xt+qq*32;
        gd.bq[dir2][qq]=WihH[dir2]+qq*32;
      }
      for(int qq=4;qq<10;qq++){
        gd.aq[dir2][qq]=h16s[dir2]+(qq-4)*32;
        gd.bq[dir2][qq]=WhhH[dir2]+(qq-4)*32;
      }
    }
    for(int qq=0;qq<4;qq++){ gd.lda[qq]=128; gd.ldb[qq]=128; }
    for(int qq=4;qq<10;qq++){ gd.lda[qq]=192; gd.ldb[qq]=192; }
    gemm_mfma<1><<<12*GYp,256,0,stream>>>(gd);
  }

  // ---- 4. JK attention + pooling + final linear ----
  jk_pool_kernel<<<G,256,0,stream>>>(xs16,xstride,score,goffs,pooled,G);
  final_kernel<<<G,128,0,stream>>>(pooled,Wl,bl,out,G);
}